// Round 2
// baseline (562.156 us; speedup 1.0000x reference)
//
#include <hip/hip_runtime.h>

// SNN residual block, fully fused:
//   GEMM1(fp32) + BN1-fold + LIF(T=4, in-reg) + spike-GEMM2 + BN2 + transposed store.
// Shapes: x[T=4][B=32][C=512][N=1024], w1[64][512], w2[32][64], out[4][4][32][8][1024].

#define T_   4
#define B_   32
#define C_   512
#define NPIX 1024
#define HID  64
#define OUTC 32
#define NT   64            // n-columns per block
#define CK   16            // c-rows per staged chunk
#define NCH  (C_ / CK)     // 32 chunks

typedef const __attribute__((address_space(1))) void* gas_t;
typedef __attribute__((address_space(3))) void* las_t;

__global__ __launch_bounds__(256, 2)
void snn_fused(const float* __restrict__ x,  const float* __restrict__ w1,
               const float* __restrict__ g1, const float* __restrict__ b1,
               const float* __restrict__ m1, const float* __restrict__ v1,
               const float* __restrict__ w2,
               const float* __restrict__ g2, const float* __restrict__ b2,
               const float* __restrict__ m2, const float* __restrict__ v2,
               float* __restrict__ out)
{
    __shared__ float xs[2][T_][CK][NT];          // 32 KB, double-buffered x tile [t][c][n]
    __shared__ float w1s[2][HID][CK];            //  8 KB, double-buffered w1 tile [o][c]
    __shared__ float w2s[HID][OUTC];             //  8 KB, w2 transposed [o][p]
    __shared__ unsigned short spk[T_][4][NT];    //  2 KB, 16-bit spike masks per (t, o-group, n)
    __shared__ float s2s[OUTC], sh2s[OUTC];

    const int tid = threadIdx.x;
    const int wv  = tid >> 6;        // wave id: phase1 = o-group, phase2 = t
    const int ln  = tid & 63;        // lane   = n within tile
    const int b   = blockIdx.y;
    const int n0  = blockIdx.x * NT;

    // ---- one-time: w2 -> LDS (transposed), BN2 fold ----
    {
        const int p  = tid & 31;
        const int ob = (tid >> 5) * 8;
        #pragma unroll
        for (int i = 0; i < 8; ++i)
            w2s[ob + i][p] = w2[p * HID + ob + i];
        if (tid < OUTC) {
            float sc  = g2[tid] / sqrtf(v2[tid] + 1e-5f);
            s2s[tid]  = sc;
            sh2s[tid] = b2[tid] - m2[tid] * sc;
        }
    }

    // ---- async staging: chunk ch of x and w1 into buffer bf ----
    // x:  wave wv loads t=wv; 4 issues of 4 c-rows x 64 n (1 KB each, lane-linear LDS dest)
    // w1: 1 issue of 16 o-rows x 16 c
    #define STAGE(ch, bf) do {                                                          \
        const int c0_ = (ch) * CK;                                                      \
        const float* gx_ = x + (((size_t)wv * B_ + b) * C_ + c0_) * NPIX + n0;          \
        _Pragma("unroll")                                                               \
        for (int j_ = 0; j_ < 4; ++j_) {                                                \
            const float* src_ = gx_ + (j_ * 4 + (ln >> 4)) * NPIX + ((ln & 15) << 2);   \
            __builtin_amdgcn_global_load_lds((gas_t)src_, (las_t)&xs[bf][wv][j_ * 4][0], 16, 0, 0); \
        }                                                                               \
        const float* sw_ = w1 + (size_t)(wv * 16 + (ln >> 2)) * C_ + c0_ + ((ln & 3) << 2); \
        __builtin_amdgcn_global_load_lds((gas_t)sw_, (las_t)&w1s[bf][wv * 16][0], 16, 0, 0); \
    } while (0)

    // ---- phase 1: GEMM1, h[t][o'] accumulators in registers ----
    float h[T_][16];
    #pragma unroll
    for (int t = 0; t < T_; ++t)
        #pragma unroll
        for (int i = 0; i < 16; ++i) h[t][i] = 0.f;

    STAGE(0, 0);
    __syncthreads();   // drains vmcnt -> chunk 0 resident

    int bf = 0;
    for (int ch = 0; ch < NCH; ++ch) {
        if (ch + 1 < NCH) STAGE(ch + 1, bf ^ 1);   // prefetch next chunk (async)
        #pragma unroll
        for (int c4 = 0; c4 < CK; c4 += 4) {
            float xv[T_][4];
            #pragma unroll
            for (int t = 0; t < T_; ++t)
                #pragma unroll
                for (int cc = 0; cc < 4; ++cc)
                    xv[t][cc] = xs[bf][t][c4 + cc][ln];          // lane-contiguous, conflict-free
            #pragma unroll
            for (int i = 0; i < 16; ++i) {
                const float4 wq = *(const float4*)&w1s[bf][wv * 16 + i][c4];  // uniform -> broadcast
                const float wa[4] = {wq.x, wq.y, wq.z, wq.w};
                #pragma unroll
                for (int cc = 0; cc < 4; ++cc)
                    #pragma unroll
                    for (int t = 0; t < T_; ++t)
                        h[t][i] = fmaf(xv[t][cc], wa[cc], h[t][i]);
            }
        }
        __syncthreads();   // chunk ch+1 staged; all reads of bf done before next overwrite
        bf ^= 1;
    }

    // ---- BN1 fold + LIF recurrence (all 4 t in registers), pack spike bits ----
    {
        unsigned int msk[T_] = {0u, 0u, 0u, 0u};
        #pragma unroll
        for (int i = 0; i < 16; ++i) {
            const int o = wv * 16 + i;
            const float sc = g1[o] / sqrtf(v1[o] + 1e-5f);   // uniform per wave -> scalar loads
            const float sh = b1[o] - m1[o] * sc;
            float v = 0.f;
            #pragma unroll
            for (int t = 0; t < T_; ++t) {
                const float hh = h[t][i] * sc + sh;
                v = v + (hh - v) * 0.5f;                     // v += (x - v)/tau, tau = 2
                const bool sp = (v >= 1.0f);
                if (sp) msk[t] |= (1u << i);
                v = sp ? 0.f : v;                            // hard reset
            }
        }
        #pragma unroll
        for (int t = 0; t < T_; ++t)
            spk[t][wv][ln] = (unsigned short)msk[t];
    }
    __syncthreads();

    // ---- phase 2: spike-GEMM2 (wave = t), BN2, transposed store ----
    {
        const int t = wv;
        const unsigned int mlo = (unsigned int)spk[t][0][ln] | ((unsigned int)spk[t][1][ln] << 16);
        const unsigned int mhi = (unsigned int)spk[t][2][ln] | ((unsigned int)spk[t][3][ln] << 16);

        float y[OUTC];
        #pragma unroll
        for (int p = 0; p < OUTC; ++p) y[p] = 0.f;

        #pragma unroll 4
        for (int o = 0; o < 32; ++o) {
            const float sp = (float)((mlo >> o) & 1u);
            #pragma unroll
            for (int p4 = 0; p4 < OUTC; p4 += 4) {
                const float4 wq = *(const float4*)&w2s[o][p4];   // uniform -> broadcast
                y[p4 + 0] = fmaf(sp, wq.x, y[p4 + 0]);
                y[p4 + 1] = fmaf(sp, wq.y, y[p4 + 1]);
                y[p4 + 2] = fmaf(sp, wq.z, y[p4 + 2]);
                y[p4 + 3] = fmaf(sp, wq.w, y[p4 + 3]);
            }
        }
        #pragma unroll 4
        for (int o = 0; o < 32; ++o) {
            const float sp = (float)((mhi >> o) & 1u);
            #pragma unroll
            for (int p4 = 0; p4 < OUTC; p4 += 4) {
                const float4 wq = *(const float4*)&w2s[o + 32][p4];
                y[p4 + 0] = fmaf(sp, wq.x, y[p4 + 0]);
                y[p4 + 1] = fmaf(sp, wq.y, y[p4 + 1]);
                y[p4 + 2] = fmaf(sp, wq.z, y[p4 + 2]);
                y[p4 + 3] = fmaf(sp, wq.w, y[p4 + 3]);
            }
        }

        // out[cg][t][b][l][n], p = cg*8 + l
        #pragma unroll
        for (int p = 0; p < OUTC; ++p) {
            const int cg = p >> 3, l = p & 7;
            const size_t idx = ((size_t)(((cg * T_ + t) * B_ + b) * 8 + l) << 10) + n0 + ln;
            out[idx] = y[p] * s2s[p] + sh2s[p];
        }
    }
    #undef STAGE
}

extern "C" void kernel_launch(void* const* d_in, const int* in_sizes, int n_in,
                              void* d_out, int out_size, void* d_ws, size_t ws_size,
                              hipStream_t stream)
{
    const float* x  = (const float*)d_in[0];
    const float* w1 = (const float*)d_in[1];
    const float* g1 = (const float*)d_in[2];
    const float* b1 = (const float*)d_in[3];
    const float* m1 = (const float*)d_in[4];
    const float* v1 = (const float*)d_in[5];
    const float* w2 = (const float*)d_in[6];
    const float* g2 = (const float*)d_in[7];
    const float* b2 = (const float*)d_in[8];
    const float* m2 = (const float*)d_in[9];
    const float* v2 = (const float*)d_in[10];

    dim3 grid(NPIX / NT, B_);   // 16 x 32 = 512 blocks, 2 per CU
    snn_fused<<<grid, 256, 0, stream>>>(x, w1, g1, b1, m1, v1, w2, g2, b2, m2, v2,
                                        (float*)d_out);
}

// Round 3
// 540.814 us; speedup vs baseline: 1.0395x; 1.0395x over previous
//
#include <hip/hip_runtime.h>

// SNN residual block, fully fused, round 3:
//  - w1/w2 operands via SCALAR loads (SGPR, K$) instead of uniform LDS reads
//    (round-2 rocprof: DS pipe was the critical path, ~140us of 305us)
//  - fp32 packed math (v_pk_fma_f32) pairing independent t-accumulators:
//    bitwise-identical per-accumulator fma order -> no spike-flip re-roll
//  - CK 16->32: half the barrier drains
// Shapes: x[4][32][512][1024], w1[64][512], w2[32][64], out[4][4][32][8][1024].

#define T_   4
#define B_   32
#define C_   512
#define NPIX 1024
#define HID  64
#define OUTC 32
#define NT   64            // n-columns per block
#define CK   32            // c-rows per staged chunk
#define NCH  (C_ / CK)     // 16 chunks

typedef const __attribute__((address_space(1))) void* gas_t;
typedef __attribute__((address_space(3))) void* las_t;
typedef float v2f __attribute__((ext_vector_type(2)));

__global__ void w2_transpose(const float* __restrict__ w2, float* __restrict__ wst)
{
    const int o = threadIdx.x;           // 0..63
    #pragma unroll
    for (int p = 0; p < OUTC; ++p)
        wst[o * OUTC + p] = w2[p * HID + o];
}

__global__ __launch_bounds__(256, 2)
void snn_fused(const float* __restrict__ x,  const float* __restrict__ w1,
               const float* __restrict__ g1, const float* __restrict__ b1,
               const float* __restrict__ m1, const float* __restrict__ v1,
               const float* __restrict__ wst,   // transposed w2 [o][p], in d_ws
               const float* __restrict__ g2, const float* __restrict__ b2,
               const float* __restrict__ m2, const float* __restrict__ v2,
               float* __restrict__ out)
{
    __shared__ float xs[2][T_][CK][NT];          // 64 KB, double-buffered x tile [t][c][n]
    __shared__ unsigned short spk[T_][4][NT];    //  2 KB, spike masks per (t, o-group, n)
    __shared__ float s2s[OUTC], sh2s[OUTC];

    const int tid = threadIdx.x;
    const int wv  = tid >> 6;        // wave id: phase1 = t (staging) / o-group (compute), phase2 = t
    const int ln  = tid & 63;        // lane   = n within tile
    const int b   = blockIdx.y;
    const int n0  = blockIdx.x * NT;
    const int wvu = __builtin_amdgcn_readfirstlane(wv);   // provably wave-uniform

    // ---- one-time: BN2 fold ----
    if (tid < OUTC) {
        float sc  = g2[tid] / sqrtf(v2[tid] + 1e-5f);
        s2s[tid]  = sc;
        sh2s[tid] = b2[tid] - m2[tid] * sc;
    }

    // ---- async staging: chunk ch of x into buffer bf (wave wv loads t=wv) ----
    #define STAGE(ch, bf) do {                                                          \
        const int c0_ = (ch) * CK;                                                      \
        const float* gx_ = x + (((size_t)wv * B_ + b) * C_ + c0_) * NPIX + n0;          \
        _Pragma("unroll")                                                               \
        for (int j_ = 0; j_ < 8; ++j_) {                                                \
            const float* src_ = gx_ + (j_ * 4 + (ln >> 4)) * NPIX + ((ln & 15) << 2);   \
            __builtin_amdgcn_global_load_lds((gas_t)src_, (las_t)&xs[bf][wv][j_ * 4][0], 16, 0, 0); \
        }                                                                               \
    } while (0)

    // ---- phase 1: GEMM1; packed accumulators h01=(t0,t1), h23=(t2,t3) per o' ----
    v2f h01[16], h23[16];
    #pragma unroll
    for (int i = 0; i < 16; ++i) { h01[i] = (v2f){0.f, 0.f}; h23[i] = (v2f){0.f, 0.f}; }

    const float* w1u = w1 + (size_t)wvu * 16 * C_;   // uniform row base -> s_load

    STAGE(0, 0);
    __syncthreads();   // drains vmcnt -> chunk 0 resident

    int bf = 0;
    for (int ch = 0; ch < NCH; ++ch) {
        if (ch + 1 < NCH) STAGE(ch + 1, bf ^ 1);   // prefetch next chunk (async)
        const float* wc = w1u + ch * CK;           // uniform
        #pragma unroll
        for (int c4 = 0; c4 < CK; c4 += 4) {
            v2f x01[4], x23[4];
            #pragma unroll
            for (int cc = 0; cc < 4; ++cc) {       // lane-contiguous b32, conflict-free
                x01[cc] = (v2f){ xs[bf][0][c4 + cc][ln], xs[bf][1][c4 + cc][ln] };
                x23[cc] = (v2f){ xs[bf][2][c4 + cc][ln], xs[bf][3][c4 + cc][ln] };
            }
            #pragma unroll
            for (int i = 0; i < 16; ++i) {
                const float* wr = wc + i * C_ + c4;      // uniform -> s_load_dwordx4
                #pragma unroll
                for (int cc = 0; cc < 4; ++cc) {
                    const v2f ws = { wr[cc], wr[cc] };   // SGPR splat (op_sel)
                    h01[i] = __builtin_elementwise_fma(x01[cc], ws, h01[i]);
                    h23[i] = __builtin_elementwise_fma(x23[cc], ws, h23[i]);
                }
            }
        }
        __syncthreads();   // chunk ch+1 staged; all reads of bf done before overwrite
        bf ^= 1;
    }

    // ---- BN1 fold + LIF recurrence (4 t in registers), pack spike bits ----
    {
        unsigned int msk[T_] = {0u, 0u, 0u, 0u};
        #pragma unroll
        for (int i = 0; i < 16; ++i) {
            const int o = wvu * 16 + i;
            const float sc = g1[o] / sqrtf(v1[o] + 1e-5f);   // uniform -> scalar loads
            const float sh = b1[o] - m1[o] * sc;
            const float hh[T_] = { h01[i].x, h01[i].y, h23[i].x, h23[i].y };
            float v = 0.f;
            #pragma unroll
            for (int t = 0; t < T_; ++t) {
                const float hb = hh[t] * sc + sh;
                v = v + (hb - v) * 0.5f;                     // v += (x - v)/tau, tau = 2
                const bool sp = (v >= 1.0f);
                if (sp) msk[t] |= (1u << i);
                v = sp ? 0.f : v;                            // hard reset
            }
        }
        #pragma unroll
        for (int t = 0; t < T_; ++t)
            spk[t][wv][ln] = (unsigned short)msk[t];
    }
    __syncthreads();

    // ---- phase 2: spike-GEMM2 (wave = t) via scalar w2t loads, BN2, store ----
    {
        const int t = wv;
        const unsigned int mlo = (unsigned int)spk[t][0][ln] | ((unsigned int)spk[t][1][ln] << 16);
        const unsigned int mhi = (unsigned int)spk[t][2][ln] | ((unsigned int)spk[t][3][ln] << 16);

        v2f y2[16];
        #pragma unroll
        for (int p2 = 0; p2 < 16; ++p2) y2[p2] = (v2f){0.f, 0.f};

        #pragma unroll 8
        for (int o = 0; o < 32; ++o) {
            const float sp = (float)((mlo >> o) & 1u);
            const v2f spv = { sp, sp };
            const float* wr = wst + o * OUTC;            // uniform -> s_load
            #pragma unroll
            for (int p2 = 0; p2 < 16; ++p2)
                y2[p2] = __builtin_elementwise_fma(spv, ((const v2f*)wr)[p2], y2[p2]);
        }
        #pragma unroll 8
        for (int o = 0; o < 32; ++o) {
            const float sp = (float)((mhi >> o) & 1u);
            const v2f spv = { sp, sp };
            const float* wr = wst + (o + 32) * OUTC;     // uniform -> s_load
            #pragma unroll
            for (int p2 = 0; p2 < 16; ++p2)
                y2[p2] = __builtin_elementwise_fma(spv, ((const v2f*)wr)[p2], y2[p2]);
        }

        // out[cg][t][b][l][n], p = cg*8 + l
        #pragma unroll
        for (int p2 = 0; p2 < 16; ++p2) {
            const float yy[2] = { y2[p2].x, y2[p2].y };
            #pragma unroll
            for (int k = 0; k < 2; ++k) {
                const int p  = p2 * 2 + k;
                const int cg = p >> 3, l = p & 7;
                const size_t idx = ((size_t)(((cg * T_ + t) * B_ + b) * 8 + l) << 10) + n0 + ln;
                out[idx] = yy[k] * s2s[p] + sh2s[p];
            }
        }
    }
    #undef STAGE
}

extern "C" void kernel_launch(void* const* d_in, const int* in_sizes, int n_in,
                              void* d_out, int out_size, void* d_ws, size_t ws_size,
                              hipStream_t stream)
{
    const float* x  = (const float*)d_in[0];
    const float* w1 = (const float*)d_in[1];
    const float* g1 = (const float*)d_in[2];
    const float* b1 = (const float*)d_in[3];
    const float* m1 = (const float*)d_in[4];
    const float* v1 = (const float*)d_in[5];
    const float* w2 = (const float*)d_in[6];
    const float* g2 = (const float*)d_in[7];
    const float* b2 = (const float*)d_in[8];
    const float* m2 = (const float*)d_in[9];
    const float* v2 = (const float*)d_in[10];

    float* wst = (float*)d_ws;                       // 64x32 transposed w2

    w2_transpose<<<1, 64, 0, stream>>>(w2, wst);
    dim3 grid(NPIX / NT, B_);                        // 16 x 32 = 512 blocks, 2 per CU
    snn_fused<<<grid, 256, 0, stream>>>(x, w1, g1, b1, m1, v1, wst, g2, b2, m2, v2,
                                        (float*)d_out);
}